// Round 13
// baseline (90.557 us; speedup 1.0000x reference)
//
#include <hip/hip_runtime.h>
#include <math.h>
#include <stdint.h>

#define B_ 8
#define T_ 256
#define N_ 128
#define K_ 64
#define NCH 64          // chunks per batch (NSTEP=4)
#define LOG128 4.852030263919617f
#define STRIDE_S 4128   // padded 16-col-block / strip stride in bytes

typedef __attribute__((ext_vector_type(2))) unsigned int u32x2;
typedef __attribute__((ext_vector_type(4))) unsigned int u32x4;
typedef __attribute__((ext_vector_type(4))) float f32x4;
typedef __attribute__((ext_vector_type(8))) short short8;

__device__ __forceinline__ uint32_t cvtpk(float lo, float hi) {
    uint32_t r;
    asm("v_cvt_pk_bf16_f32 %0, %1, %2" : "=v"(r) : "v"(lo), "v"(hi));
    return r;
}
__device__ __forceinline__ float blo(uint32_t w) { return __uint_as_float(w << 16); }
__device__ __forceinline__ float bhi(uint32_t w) { return __uint_as_float(w & 0xffff0000u); }

#define TRRD(dst, addr) asm volatile("ds_read_b64_tr_b16 %0, %1" : "=v"(dst) : "v"(addr) : "memory")
#define WAITL8  { asm volatile("s_waitcnt lgkmcnt(8)"  ::: "memory"); __builtin_amdgcn_sched_barrier(0); }
#define WAITL0  { asm volatile("s_waitcnt lgkmcnt(0)"  ::: "memory"); __builtin_amdgcn_sched_barrier(0); }
// Barrier with LDS-only drain: global prefetch loads stay in flight across it.
#define BARRIER_LG() { asm volatile("s_waitcnt lgkmcnt(0)" ::: "memory"); \
                       __builtin_amdgcn_s_barrier(); \
                       __builtin_amdgcn_sched_barrier(0); }

// ---------------- Kernel 1: emission probabilities (softmax of obs @ W + b) ----------------
__global__ __launch_bounds__(128) void k_emit(
    const float* __restrict__ obs,    // [B,T,K]
    const int*   __restrict__ dur,    // [B]
    const float* __restrict__ W,      // [K,N]
    const float* __restrict__ bias,   // [N]
    float* __restrict__ e)            // [B,T,N] softmax probs
{
    int bt = blockIdx.x;
    int b  = bt >> 8;
    int t  = bt & 255;
    if (t >= dur[b]) return;
    int n = threadIdx.x;
    __shared__ float o[K_];
    __shared__ float wmax[2];
    __shared__ float wsum[2];
    if (n < K_) o[n] = obs[(size_t)bt * K_ + n];
    __syncthreads();
    float acc = bias[n];
    #pragma unroll
    for (int k = 0; k < K_; ++k)
        acc = fmaf(o[k], W[k * N_ + n], acc);
    float m = acc;
    #pragma unroll
    for (int off = 32; off; off >>= 1) m = fmaxf(m, __shfl_xor(m, off));
    int w = n >> 6;
    if ((n & 63) == 0) wmax[w] = m;
    __syncthreads();
    float M = fmaxf(wmax[0], wmax[1]);
    float ex = expf(acc - M);
    float s = ex;
    #pragma unroll
    for (int off = 32; off; off >>= 1) s += __shfl_xor(s, off);
    if ((n & 63) == 0) wsum[w] = s;
    __syncthreads();
    float S = wsum[0] + wsum[1];
    e[(size_t)bt * N_ + n] = ex / S;
}

// ---------------- Kernel 2: 4-step chunk products via MFMA, live-compacted grid ----------------
// Live chunks (b,c) are compacted onto blockIdx 0..L-1 so ~all 256 CUs stream
// concurrently (dead blocks previously idled half the machine).
// Math/layout identical to the verified round-5..12 path, NSTEP=8 -> 4.
__global__ __launch_bounds__(512, 1) void k_chunk(
    const float* __restrict__ trans,  // [T,B,N,N]
    const int*   __restrict__ dur,
    const float* __restrict__ e,      // [B,T,N]
    uint32_t* __restrict__ gout)      // [B][NCH][8192] u32
{
    // ---- live-chunk remap: block i takes the i-th live (b,c) pair
    int b = -1, c = 0, accn = 0;
    #pragma unroll
    for (int bb = 0; bb < 8; ++bb) {
        int db = dur[bb];
        int nb = (db > 1) ? ((db + 2) >> 2) : 0;      // ceil((db-1)/4)
        if (b < 0 && (int)blockIdx.x < accn + nb) { b = bb; c = (int)blockIdx.x - accn; }
        accn += nb;
    }
    if (b < 0) return;
    const int d  = dur[b];
    const int t0 = c * 4 + 1;
    int te = c * 4 + 4; if (te > d - 1) te = d - 1;

    const int tid  = threadIdx.x;
    const int lane = tid & 63;
    const int wv   = tid >> 6;
    const int cc   = lane & 15;
    const int gq   = lane >> 4;

    __shared__ __align__(16) uint8_t ldsC[2][8 * STRIDE_S];
    __shared__ __align__(16) uint8_t strips[8 * STRIDE_S];

    {
        uint32_t* sw = (uint32_t*)(strips + wv * STRIDE_S);
        #pragma unroll
        for (int i = 0; i < 16; ++i) sw[lane + i * 64] = 0;
        if (lane < 16)
            ((uint16_t*)(strips + wv * STRIDE_S))[(16 * wv + lane) * 16 + lane] = 0x3F80u;
    }

    const uint32_t sbase = (uint32_t)(uintptr_t)&strips[wv * STRIDE_S];
    const uint32_t lt    = (uint32_t)(cc * 2 + gq * 256);
    const int row0 = tid >> 5;
    const int jbp  = (tid & 31) >> 2;
    const int cc0  = (tid & 3) << 2;

    float4 vA[8], vB[8];
    float  eA[8], eB[8];
    {
        const float4* gp = (const float4*)(trans + (((size_t)t0 * B_ + b) << 14));
        #pragma unroll
        for (int i = 0; i < 8; ++i) vA[i] = gp[tid + i * 512];
        #pragma unroll
        for (int i = 0; i < 8; ++i)
            eA[i] = e[((size_t)b * T_ + (t0 - 1)) * N_ + row0 + i * 16];
    }
    if (t0 + 1 <= te) {
        const float4* gp = (const float4*)(trans + (((size_t)(t0 + 1) * B_ + b) << 14));
        #pragma unroll
        for (int i = 0; i < 8; ++i) vB[i] = gp[tid + i * 512];
        #pragma unroll
        for (int i = 0; i < 8; ++i)
            eB[i] = e[((size_t)b * T_ + t0) * N_ + row0 + i * 16];
    }

    int buf = 0;

#define ISSUE_B(S, JB) { \
        _Pragma("unroll") \
        for (int kb = 0; kb < 4; ++kb) { \
            uint32_t bd = cbase + (uint32_t)((JB) * STRIDE_S + kb * 1024) + lt; \
            TRRD(rb[S][2 * kb],     bd); \
            TRRD(rb[S][2 * kb + 1], bd + 128); } }
#define MFMA_JB(JB, S) { \
        f32x4 d4 = (f32x4){0.f, 0.f, 0.f, 0.f}; \
        _Pragma("unroll") \
        for (int kb = 0; kb < 4; ++kb) { \
            u32x4 tmp = (u32x4){rb[S][2 * kb].x, rb[S][2 * kb].y, rb[S][2 * kb + 1].x, rb[S][2 * kb + 1].y}; \
            short8 Bf = __builtin_bit_cast(short8, tmp); \
            d4 = __builtin_amdgcn_mfma_f32_16x16x32_bf16(A[kb], Bf, d4, 0, 0, 0); } \
        acc[JB] = d4; }

#define STEP(VC, EC) { \
    uint8_t* cb = ldsC[buf]; \
    const uint32_t cbase = (uint32_t)(uintptr_t)cb; \
    _Pragma("unroll") \
    for (int i = 0; i < 8; ++i) { \
        float ps = (VC[i].x + VC[i].y) + (VC[i].z + VC[i].w); \
        ps += __shfl_xor(ps, 1); \
        ps += __shfl_xor(ps, 2); \
        ps += __shfl_xor(ps, 4); \
        ps += __shfl_xor(ps, 8); \
        ps += __shfl_xor(ps, 16); \
        float sc = 128.0f * EC[i] * __builtin_amdgcn_rcpf(ps); \
        uint32_t p0 = cvtpk(VC[i].x * sc, VC[i].y * sc); \
        uint32_t p1 = cvtpk(VC[i].z * sc, VC[i].w * sc); \
        *(uint2*)(cb + jbp * STRIDE_S + (row0 + i * 16) * 32 + cc0 * 2) = make_uint2(p0, p1); \
    } \
    if (t + 2 <= te) { \
        const float4* gp = (const float4*)(trans + (((size_t)(t + 2) * B_ + b) << 14)); \
        _Pragma("unroll") \
        for (int i = 0; i < 8; ++i) VC[i] = gp[tid + i * 512]; \
        _Pragma("unroll") \
        for (int i = 0; i < 8; ++i) \
            EC[i] = e[((size_t)b * T_ + (t + 1)) * N_ + row0 + i * 16]; \
    } \
    BARRIER_LG(); \
    { \
        u32x2 ra[8]; \
        _Pragma("unroll") \
        for (int kb = 0; kb < 4; ++kb) { \
            uint32_t ad = sbase + (uint32_t)(kb * 1024) + lt; \
            TRRD(ra[2 * kb],     ad); \
            TRRD(ra[2 * kb + 1], ad + 128); \
        } \
        u32x2 rb[2][8]; \
        f32x4 acc[8]; \
        ISSUE_B(0, 0); \
        ISSUE_B(1, 1); \
        WAITL8; \
        short8 A[4]; \
        _Pragma("unroll") \
        for (int kb = 0; kb < 4; ++kb) { \
            u32x4 tmp = (u32x4){ra[2 * kb].x, ra[2 * kb].y, ra[2 * kb + 1].x, ra[2 * kb + 1].y}; \
            A[kb] = __builtin_bit_cast(short8, tmp); \
        } \
        MFMA_JB(0, 0); \
        ISSUE_B(0, 2); WAITL8; MFMA_JB(1, 1); \
        ISSUE_B(1, 3); WAITL8; MFMA_JB(2, 0); \
        ISSUE_B(0, 4); WAITL8; MFMA_JB(3, 1); \
        ISSUE_B(1, 5); WAITL8; MFMA_JB(4, 0); \
        ISSUE_B(0, 6); WAITL8; MFMA_JB(5, 1); \
        ISSUE_B(1, 7); WAITL8; MFMA_JB(6, 0); \
        WAITL0;                MFMA_JB(7, 1); \
        _Pragma("unroll") \
        for (int jb = 0; jb < 8; ++jb) { \
            uint32_t p0 = cvtpk(acc[jb][0], acc[jb][1]); \
            uint32_t p1 = cvtpk(acc[jb][2], acc[jb][3]); \
            *(uint2*)(strips + wv * STRIDE_S + (jb * 16 + cc) * 32 + gq * 8) = make_uint2(p0, p1); \
        } \
    } \
    buf ^= 1; \
}

    int t = t0;
    while (true) {
        STEP(vA, eA); ++t; if (t > te) break;
        STEP(vB, eB); ++t; if (t > te) break;
    }
#undef STEP
#undef ISSUE_B
#undef MFMA_JB

    // ---- export G row-major bf16 (rows = contraction dim, as consumed by k_comb)
    uint32_t* gdst = gout + ((size_t)(b * NCH + c) << 13);
    #pragma unroll
    for (int kb = 0; kb < 4; ++kb) {
        u32x2 e0, e1;
        uint32_t ad = sbase + (uint32_t)(kb * 1024) + lt;
        TRRD(e0, ad);
        TRRD(e1, ad + 128);
        WAITL0;
        u32x4 o = (u32x4){e0.x, e0.y, e1.x, e1.y};
        *(u32x4*)(gdst + (size_t)((16 * wv + cc) * 64 + kb * 16 + gq * 4)) = o;
    }
}

// ---------------- Kernel 3: serial combine, column-split (4 waves, 1 barrier/chunk) --------
// Wave w owns output cols [32w,32w+32). Lane l covers rows (l>>2)+16i (b128 loads),
// in-wave shfl reduce over the 16-lane row-groups. Lagged rescale: kick even chunk,
// combine odd, apply next even (exact: S -= log(applied mr)).
__global__ __launch_bounds__(256, 1) void k_comb(
    const uint32_t* __restrict__ gtiles, // [B][NCH][8192] u32, rows = contraction dim
    const int*   __restrict__ dur,
    const float* __restrict__ sp,        // [B,N]
    const float* __restrict__ e,         // [B,T,N]
    float* __restrict__ out)             // [B]
{
    const int b   = blockIdx.x;
    const int tid = threadIdx.x;
    const int wv  = tid >> 6;
    const int l   = tid & 63;
    const int lr  = l >> 2;              // row-group 0..15
    const int lq  = l & 3;               // col-quad 0..3
    const int d   = dur[b];
    const int nc  = (d + 2) >> 2;        // ceil((d-1)/4)  (d>=1)

    __shared__ float gl[2][N_];
    __shared__ float wmb[2][8];

    if (tid < 64)
        *(float2*)&gl[0][2 * tid] = make_float2(sp[b * N_ + 2 * tid], sp[b * N_ + 2 * tid + 1]);
    __syncthreads();

    float S = -(float)(d - 1) * LOG128;
    float mrApply = 1.0f;

    const uint32_t* gb = gtiles + (((size_t)b * NCH) << 13);
    const int loff = lr * 64 + 16 * wv + 4 * lq;   // u32 offset of lane's first b128

    u32x4 bufA[8], bufB[8], bufC[8], bufD[8];

#define LOADCH(P, C) { \
    const uint32_t* gp_ = gb + ((size_t)(C) << 13) + loff; \
    _Pragma("unroll") \
    for (int i = 0; i < 8; ++i) P[i] = *(const u32x4*)(gp_ + i * 1024); }

#define RED(x) { x += __shfl_xor(x, 4); x += __shfl_xor(x, 8); \
                 x += __shfl_xor(x, 16); x += __shfl_xor(x, 32); }

#define CSTEP(CUR, NXT, CIDX) { \
    if ((CIDX) + 3 < nc) LOADCH(NXT, (CIDX) + 3); \
    const int p_ = (CIDX) & 1; \
    float a0 = 0.f, a1 = 0.f, a2 = 0.f, a3 = 0.f; \
    float a4 = 0.f, a5 = 0.f, a6 = 0.f, a7 = 0.f; \
    _Pragma("unroll") \
    for (int i = 0; i < 8; ++i) { \
        float g = gl[p_][lr + 16 * i]; \
        u32x4 r = CUR[i]; \
        a0 = fmaf(blo(r.x), g, a0); a1 = fmaf(bhi(r.x), g, a1); \
        a2 = fmaf(blo(r.y), g, a2); a3 = fmaf(bhi(r.y), g, a3); \
        a4 = fmaf(blo(r.z), g, a4); a5 = fmaf(bhi(r.z), g, a5); \
        a6 = fmaf(blo(r.w), g, a6); a7 = fmaf(bhi(r.w), g, a7); \
    } \
    RED(a0) RED(a1) RED(a2) RED(a3) RED(a4) RED(a5) RED(a6) RED(a7) \
    if ((p_ == 0) && (CIDX) >= 2) { \
        a0 *= mrApply; a1 *= mrApply; a2 *= mrApply; a3 *= mrApply; \
        a4 *= mrApply; a5 *= mrApply; a6 *= mrApply; a7 *= mrApply; \
        S -= __logf(mrApply); \
    } \
    if (p_ == 0) { \
        float m_ = fmaxf(fmaxf(fmaxf(a0, a1), fmaxf(a2, a3)), \
                         fmaxf(fmaxf(a4, a5), fmaxf(a6, a7))); \
        m_ = fmaxf(m_, __shfl_xor(m_, 1)); \
        m_ = fmaxf(m_, __shfl_xor(m_, 2)); \
        if (l == 0) wmb[((CIDX) >> 1) & 1][wv] = m_; \
    } \
    if (lr == 0) { \
        *(float4*)&gl[p_ ^ 1][32 * wv + 8 * lq]     = make_float4(a0, a1, a2, a3); \
        *(float4*)&gl[p_ ^ 1][32 * wv + 8 * lq + 4] = make_float4(a4, a5, a6, a7); \
    } \
    BARRIER_LG(); \
    if (p_ == 1) { \
        float4 wm = *(const float4*)&wmb[((CIDX) >> 1) & 1][0]; \
        float mx = fmaxf(fmaxf(wm.x, wm.y), fmaxf(wm.z, wm.w)); \
        mrApply = __builtin_amdgcn_rcpf(fmaxf(mx, 1e-35f)); \
    } \
}

    if (nc > 0) {
        LOADCH(bufA, 0);
        if (nc > 1) LOADCH(bufB, 1);
        if (nc > 2) LOADCH(bufC, 2);
        int c = 0;
        while (true) {
            CSTEP(bufA, bufD, c); ++c; if (c >= nc) break;
            CSTEP(bufB, bufA, c); ++c; if (c >= nc) break;
            CSTEP(bufC, bufB, c); ++c; if (c >= nc) break;
            CSTEP(bufD, bufC, c); ++c; if (c >= nc) break;
        }
    }
#undef LOADCH
#undef RED
#undef CSTEP

    // ---- final: out[b] = S + log(sum_j gamma[j] * e[d-1][j])
    const int pf = nc & 1;
    float g0 = gl[pf][2 * l];
    float g1 = gl[pf][2 * l + 1];
    float e0 = e[((size_t)b * T_ + (d - 1)) * N_ + 2 * l];
    float e1 = e[((size_t)b * T_ + (d - 1)) * N_ + 2 * l + 1];
    float sv = g0 * e0 + g1 * e1;
    #pragma unroll
    for (int of = 1; of < 64; of <<= 1) sv += __shfl_xor(sv, of);
    if (tid == 0) out[b] = S + logf(sv);
}

extern "C" void kernel_launch(void* const* d_in, const int* in_sizes, int n_in,
                              void* d_out, int out_size, void* d_ws, size_t ws_size,
                              hipStream_t stream) {
    const float* obs   = (const float*)d_in[0];   // [B,T,K]
    const int*   dur   = (const int*)  d_in[1];   // [B]
    const float* trans = (const float*)d_in[2];   // [T,B,N,N]
    const float* sp    = (const float*)d_in[3];   // [B,N]
    const float* W     = (const float*)d_in[4];   // [K,N]
    const float* bias  = (const float*)d_in[5];   // [N]
    float* out = (float*)d_out;

    float* e = (float*)d_ws;                                   // 1 MB
    uint32_t* gout = (uint32_t*)((char*)d_ws + (size_t)B_ * T_ * N_ * 4);  // 16 MB

    hipLaunchKernelGGL(k_emit,  dim3(B_ * T_),   dim3(128), 0, stream, obs, dur, W, bias, e);
    hipLaunchKernelGGL(k_chunk, dim3(B_ * NCH),  dim3(512), 0, stream, trans, dur, e, gout);
    hipLaunchKernelGGL(k_comb,  dim3(B_),        dim3(256), 0, stream, gout, dur, sp, e, out);
}